// Round 9
// baseline (107.373 us; speedup 1.0000x reference)
//
#include <hip/hip_runtime.h>

#define B_  2
#define T_  2048
#define D_  512
#define H_  8
#define HD_ 64
#define WHALF_ 16
#define Mtot (B_*T_)
#define QKV_LD 1536

typedef __attribute__((ext_vector_type(8))) short short8;   // 8 bf16 in 4 VGPRs
typedef __attribute__((ext_vector_type(4))) short short4v;
typedef __attribute__((ext_vector_type(4))) float floatx4;  // MFMA accumulator

__device__ __forceinline__ unsigned short f2bf(float f) {
    unsigned u = __float_as_uint(f);
    u = (u + 0x7fffu + ((u >> 16) & 1u)) >> 16;   // RNE
    return (unsigned short)u;
}

__device__ __forceinline__ void glds16(const unsigned short* g, unsigned short* l) {
    // async global->LDS, 16 B/lane; LDS dest = wave-uniform base + lane*16
    __builtin_amdgcn_global_load_lds(
        (const __attribute__((address_space(1))) void*)g,
        (__attribute__((address_space(3))) void*)l, 16, 0, 0);
}

// ---------------------------------------------------------------------------
// Fused cast kernel (unchanged).
// ---------------------------------------------------------------------------
__global__ __launch_bounds__(256) void cast_all(
    const float* __restrict__ x,
    const float* __restrict__ Wq, const float* __restrict__ Wk,
    const float* __restrict__ Wv, const float* __restrict__ Wo,
    const float* __restrict__ bq, const float* __restrict__ bk,
    const float* __restrict__ bv,
    unsigned short* __restrict__ xb,
    unsigned short* __restrict__ wqkv, unsigned short* __restrict__ wob,
    float* __restrict__ bqkv)
{
    if (blockIdx.x < 2048) {
        int i = blockIdx.x * 256 + threadIdx.x;
        float4 f = ((const float4*)x)[i];
        ushort4 o;
        o.x = f2bf(f.x); o.y = f2bf(f.y); o.z = f2bf(f.z); o.w = f2bf(f.w);
        ((ushort4*)xb)[i] = o;
    } else if (blockIdx.x < 3072) {
        int gid = (blockIdx.x - 2048) * 256 + threadIdx.x;
        int m   = gid >> 16;
        int idx = gid & 0xFFFF;
        const float* src = (m == 0) ? Wq : (m == 1) ? Wk : (m == 2) ? Wv : Wo;
        float4 f = ((const float4*)src)[idx];
        ushort4 o;
        o.x = f2bf(f.x); o.y = f2bf(f.y); o.z = f2bf(f.z); o.w = f2bf(f.w);
        if (m < 3) ((ushort4*)wqkv)[(m << 16) + idx] = o;
        else       ((ushort4*)wob)[idx] = o;
    } else {
        for (int i = threadIdx.x; i < 384; i += 256) {
            const float* src = (i < 128) ? bq : (i < 256) ? bk : bv;
            ((float4*)bqkv)[i] = ((const float4*)src)[i & 127];
        }
    }
}

// ---------------------------------------------------------------------------
// Shared GEMM body: tile 64x64, BK=128 (4 K-iters, 4 barrier drains), glds
// staging with granule swizzle: logical 16B-granule g of row r lives at
// physical granule g^(r&7). Staging chunk = 4 rows x 256 B (1 KB); 16 chunks
// per 64x128 tile, 4 per wave. Fragment reads (granule ks*4+quad, rows
// tile*16+lo) hit 8 distinct bank-quads -> 2-way only (free, m136).
// LDS 32 KB -> 5 blocks/CU.
// ---------------------------------------------------------------------------
// GEMM1: qkvb[4096,1536](bf16) = xb @ wqkv^T + bqkv. 1536 blocks.
__global__ __launch_bounds__(256) void gemm_qkv(
    const unsigned short* __restrict__ A, const unsigned short* __restrict__ W,
    const float* __restrict__ bias, unsigned short* __restrict__ C)
{
    __shared__ unsigned short As[64 * 128];   // 16 KB
    __shared__ unsigned short Bs[64 * 128];   // 16 KB

    const int t  = threadIdx.x;
    const int m0 = blockIdx.x * 64;
    const int n0 = blockIdx.y * 64;          // global col in [0,1536)
    const int w  = t >> 6, l = t & 63;
    const int quad = l >> 4, lo = l & 15;

    const int ric = l >> 4;                  // row in 4-row chunk
    const int pcg = l & 15;                  // physical 16B-granule
    const unsigned short* Ag[4]; unsigned short* ldsA[4];
    const unsigned short* Bg[4]; unsigned short* ldsB[4];
    #pragma unroll
    for (int p = 0; p < 4; ++p) {
        int c   = 4 * w + p;                 // chunk 0..15
        int row = 4 * c + ric;               // 0..63
        int lcg = pcg ^ (row & 7);           // logical granule this lane fetches
        Ag[p]   = A + (size_t)(m0 + row) * 512 + lcg * 8;
        ldsA[p] = &As[(4 * c) * 128];
        Bg[p]   = W + (size_t)(n0 + row) * 512 + lcg * 8;
        ldsB[p] = &Bs[(4 * c) * 128];
    }

    floatx4 acc[4];
    #pragma unroll
    for (int j = 0; j < 4; ++j) acc[j] = (floatx4)0.0f;

    const int swlo = lo & 7;

    for (int k0 = 0; k0 < 512; k0 += 128) {
        #pragma unroll
        for (int p = 0; p < 4; ++p) { glds16(Ag[p] + k0, ldsA[p]); glds16(Bg[p] + k0, ldsB[p]); }
        __syncthreads();

        #pragma unroll
        for (int ks = 0; ks < 4; ++ks) {
            const int cg = ((ks * 4 + quad) ^ swlo) * 8;
            short8 a = *(const short8*)(&As[(w * 16 + lo) * 128 + cg]);
            #pragma unroll
            for (int j = 0; j < 4; ++j) {
                short8 b = *(const short8*)(&Bs[(j * 16 + lo) * 128 + cg]);
                acc[j] = __builtin_amdgcn_mfma_f32_16x16x32_bf16(a, b, acc[j], 0, 0, 0);
            }
        }
        __syncthreads();
    }

    #pragma unroll
    for (int j = 0; j < 4; ++j) {
        int col = n0 + j * 16 + lo;
        float bv = bias[col];
        #pragma unroll
        for (int r = 0; r < 4; ++r) {
            int row = m0 + w * 16 + quad * 4 + r;
            C[(size_t)row * QKV_LD + col] = f2bf(acc[j][r] + bv);
        }
    }
}

// GEMM2: out[4096,512](f32) = attb(bf16) @ wob^T + bo. 512 blocks.
__global__ __launch_bounds__(256) void gemm_out(
    const unsigned short* __restrict__ attb, const unsigned short* __restrict__ wob,
    const float* __restrict__ bo, float* __restrict__ out)
{
    __shared__ unsigned short As[64 * 128];
    __shared__ unsigned short Bs[64 * 128];

    const int t  = threadIdx.x;
    const int m0 = blockIdx.x * 64;
    const int n0 = blockIdx.y * 64;
    const int w  = t >> 6, l = t & 63;
    const int quad = l >> 4, lo = l & 15;

    const int ric = l >> 4;
    const int pcg = l & 15;
    const unsigned short* Ag[4]; unsigned short* ldsA[4];
    const unsigned short* Bg[4]; unsigned short* ldsB[4];
    #pragma unroll
    for (int p = 0; p < 4; ++p) {
        int c   = 4 * w + p;
        int row = 4 * c + ric;
        int lcg = pcg ^ (row & 7);
        Ag[p]   = attb + (size_t)(m0 + row) * 512 + lcg * 8;
        ldsA[p] = &As[(4 * c) * 128];
        Bg[p]   = wob + (size_t)(n0 + row) * 512 + lcg * 8;
        ldsB[p] = &Bs[(4 * c) * 128];
    }

    floatx4 acc[4];
    #pragma unroll
    for (int j = 0; j < 4; ++j) acc[j] = (floatx4)0.0f;

    const int swlo = lo & 7;

    for (int k0 = 0; k0 < 512; k0 += 128) {
        #pragma unroll
        for (int p = 0; p < 4; ++p) { glds16(Ag[p] + k0, ldsA[p]); glds16(Bg[p] + k0, ldsB[p]); }
        __syncthreads();

        #pragma unroll
        for (int ks = 0; ks < 4; ++ks) {
            const int cg = ((ks * 4 + quad) ^ swlo) * 8;
            short8 a = *(const short8*)(&As[(w * 16 + lo) * 128 + cg]);
            #pragma unroll
            for (int j = 0; j < 4; ++j) {
                short8 b = *(const short8*)(&Bs[(j * 16 + lo) * 128 + cg]);
                acc[j] = __builtin_amdgcn_mfma_f32_16x16x32_bf16(a, b, acc[j], 0, 0, 0);
            }
        }
        __syncthreads();
    }

    #pragma unroll
    for (int j = 0; j < 4; ++j) {
        int col = n0 + j * 16 + lo;
        float bv = bo[col];
        #pragma unroll
        for (int r = 0; r < 4; ++r) {
            int row = m0 + w * 16 + quad * 4 + r;
            out[(size_t)row * 512 + col] = acc[j][r] + bv;
        }
    }
}

// ---------------------------------------------------------------------------
// MFMA local-window attention, band-restricted (unchanged from R8).
// ---------------------------------------------------------------------------
#define QLD 72
#define VLD 76

__global__ __launch_bounds__(256) void attn_mfma(
    const unsigned short* __restrict__ qkv, unsigned short* __restrict__ att)
{
    __shared__ unsigned short Qs[64][QLD];
    __shared__ unsigned short Ks[96][QLD];
    __shared__ unsigned short Vs[96][VLD];
    __shared__ unsigned short Pws[4][16][QLD];

    const int q0 = blockIdx.x * 64;
    const int bh = blockIdx.y;
    const int b = bh >> 3, h = bh & 7;
    const int t = threadIdx.x;
    const int wq = t >> 6, l = t & 63;
    const int quad = l >> 4, lo = l & 15;

    const size_t baseQ = (size_t)(b * T_) * QKV_LD + h * HD_;

    for (int c = t; c < 512; c += 256) {
        int row = c >> 3, cg = c & 7;
        *(short8*)(&Qs[row][cg * 8]) =
            *(const short8*)(&qkv[baseQ + (size_t)(q0 + row) * QKV_LD + cg * 8]);
    }
    for (int c = t; c < 768; c += 256) {
        int row = c >> 3, cg = c & 7;
        int g = q0 - WHALF_ + row;
        short8 kv = (short8)(short)0;
        if (g >= 0 && g < T_)
            kv = *(const short8*)(&qkv[baseQ + 512 + (size_t)g * QKV_LD + cg * 8]);
        *(short8*)(&Ks[row][cg * 8]) = kv;
    }
    for (int c = t; c < 768; c += 256) {
        int row = c >> 3, cg = c & 7;
        int g = q0 - WHALF_ + row;
        short8 vv = (short8)(short)0;
        if (g >= 0 && g < T_)
            vv = *(const short8*)(&qkv[baseQ + 1024 + (size_t)g * QKV_LD + cg * 8]);
        short4v lo4 = { vv[0], vv[1], vv[2], vv[3] };
        short4v hi4 = { vv[4], vv[5], vv[6], vv[7] };
        *(short4v*)(&Vs[row][cg * 8])     = lo4;
        *(short4v*)(&Vs[row][cg * 8 + 4]) = hi4;
    }
    __syncthreads();

    const int ks0 = wq >> 1;
    const int kb  = ks0 * 2;

    floatx4 S[4];
    #pragma unroll
    for (int tt = 0; tt < 4; ++tt) S[tt] = (floatx4)0.0f;
    short8 aq[2];
    #pragma unroll
    for (int ks = 0; ks < 2; ++ks)
        aq[ks] = *(const short8*)(&Qs[wq * 16 + lo][ks * 32 + quad * 8]);
    #pragma unroll
    for (int tt = 0; tt < 4; ++tt) {
        #pragma unroll
        for (int ks = 0; ks < 2; ++ks) {
            short8 bk8 = *(const short8*)(&Ks[(kb + tt) * 16 + lo][ks * 32 + quad * 8]);
            S[tt] = __builtin_amdgcn_mfma_f32_16x16x32_bf16(aq[ks], bk8, S[tt], 0, 0, 0);
        }
    }

    float inv_r[4];
    #pragma unroll
    for (int r = 0; r < 4; ++r) {
        int qi = q0 + wq * 16 + quad * 4 + r;
        float mx = -1e30f;
        float sv[4]; bool vd[4];
        #pragma unroll
        for (int tt = 0; tt < 4; ++tt) {
            int j = q0 - WHALF_ + (kb + tt) * 16 + lo;
            bool ok = (j >= qi - WHALF_) && (j < qi + WHALF_) && (j >= 0) && (j < T_);
            float s = S[tt][r] * 0.125f;
            sv[tt] = s; vd[tt] = ok;
            mx = (ok && s > mx) ? s : mx;
        }
        #pragma unroll
        for (int mm = 1; mm < 16; mm <<= 1) mx = fmaxf(mx, __shfl_xor(mx, mm, 16));
        float den = 0.f;
        #pragma unroll
        for (int tt = 0; tt < 4; ++tt) {
            float e = vd[tt] ? __expf(sv[tt] - mx) : 0.f;
            Pws[wq][quad * 4 + r][tt * 16 + lo] = f2bf(e);
            den += e;
        }
        #pragma unroll
        for (int mm = 1; mm < 16; mm <<= 1) den += __shfl_xor(den, mm, 16);
        inv_r[r] = 1.0f / den;
    }
    // Pws is wave-private: in-wave lgkmcnt ordering suffices, no barrier.

    floatx4 O[4];
    #pragma unroll
    for (int nt = 0; nt < 4; ++nt) O[nt] = (floatx4)0.0f;
    #pragma unroll
    for (int ksr = 0; ksr < 2; ++ksr) {
        short8 ap = *(const short8*)(&Pws[wq][lo][ksr * 32 + quad * 8]);
        const int krow = (ks0 + ksr) * 32 + quad * 8;
        #pragma unroll
        for (int nt = 0; nt < 4; ++nt) {
            short8 bv8;
            #pragma unroll
            for (int j = 0; j < 8; ++j)
                bv8[j] = (short)Vs[krow + j][nt * 16 + lo];
            O[nt] = __builtin_amdgcn_mfma_f32_16x16x32_bf16(ap, bv8, O[nt], 0, 0, 0);
        }
    }

    #pragma unroll
    for (int r = 0; r < 4; ++r) {
        int qi = q0 + wq * 16 + quad * 4 + r;
        size_t rowb = (size_t)(b * T_ + qi) * D_ + h * HD_;
        #pragma unroll
        for (int nt = 0; nt < 4; ++nt)
            att[rowb + nt * 16 + lo] = f2bf(O[nt][r] * inv_r[r]);
    }
}

// ---------------------------------------------------------------------------
extern "C" void kernel_launch(void* const* d_in, const int* in_sizes, int n_in,
                              void* d_out, int out_size, void* d_ws, size_t ws_size,
                              hipStream_t stream) {
    const float* x  = (const float*)d_in[0];
    const float* Wq = (const float*)d_in[1];
    const float* bq = (const float*)d_in[2];
    const float* Wk = (const float*)d_in[3];
    const float* bk = (const float*)d_in[4];
    const float* Wv = (const float*)d_in[5];
    const float* bv = (const float*)d_in[6];
    const float* Wo = (const float*)d_in[7];
    const float* bo = (const float*)d_in[8];
    float* out = (float*)d_out;

    char* ws = (char*)d_ws;
    unsigned short* xb   = (unsigned short*)(ws);                 //  4.00 MB
    unsigned short* wqkv = (unsigned short*)(ws +  4194304);      //  1.50 MB
    unsigned short* wob  = (unsigned short*)(ws +  5767168);      //  0.50 MB
    float*          bqkv = (float*)         (ws +  6291456);      //  6 KB
    unsigned short* qkvb = (unsigned short*)(ws +  6297600);      // 12.00 MB
    unsigned short* attb = (unsigned short*)(ws + 18880512);      //  4.00 MB

    cast_all<<<3073, 256, 0, stream>>>(x, Wq, Wk, Wv, Wo, bq, bk, bv,
                                       xb, wqkv, wob, bqkv);

    // fused QKV projection: 1536 blocks, BK=128 (4 K-iters)
    gemm_qkv<<<dim3(Mtot / 64, QKV_LD / 64), 256, 0, stream>>>(
        xb, wqkv, bqkv, qkvb);

    // local attention (band-restricted MFMA)
    attn_mfma<<<dim3(T_ / 64, B_ * H_), 256, 0, stream>>>(qkvb, attb);

    // output projection: 512 blocks, BK=128
    gemm_out<<<dim3(Mtot / 64, D_ / 64), 256, 0, stream>>>(attb, wob, bo, out);
}

// Round 10
// 106.365 us; speedup vs baseline: 1.0095x; 1.0095x over previous
//
#include <hip/hip_runtime.h>

#define B_  2
#define T_  2048
#define D_  512
#define H_  8
#define HD_ 64
#define WHALF_ 16
#define Mtot (B_*T_)
#define QKV_LD 1536

typedef __attribute__((ext_vector_type(8))) short short8;   // 8 bf16 in 4 VGPRs
typedef __attribute__((ext_vector_type(4))) short short4v;
typedef __attribute__((ext_vector_type(4))) float floatx4;  // MFMA accumulator

__device__ __forceinline__ unsigned short f2bf(float f) {
    unsigned u = __float_as_uint(f);
    u = (u + 0x7fffu + ((u >> 16) & 1u)) >> 16;   // RNE
    return (unsigned short)u;
}

__device__ __forceinline__ void glds16(const unsigned short* g, unsigned short* l) {
    // async global->LDS, 16 B/lane; LDS dest = wave-uniform base + lane*16
    __builtin_amdgcn_global_load_lds(
        (const __attribute__((address_space(1))) void*)g,
        (__attribute__((address_space(3))) void*)l, 16, 0, 0);
}

// ---------------------------------------------------------------------------
// Fused cast kernel.
// ---------------------------------------------------------------------------
__global__ __launch_bounds__(256) void cast_all(
    const float* __restrict__ x,
    const float* __restrict__ Wq, const float* __restrict__ Wk,
    const float* __restrict__ Wv, const float* __restrict__ Wo,
    const float* __restrict__ bq, const float* __restrict__ bk,
    const float* __restrict__ bv,
    unsigned short* __restrict__ xb,
    unsigned short* __restrict__ wqkv, unsigned short* __restrict__ wob,
    float* __restrict__ bqkv)
{
    if (blockIdx.x < 2048) {
        int i = blockIdx.x * 256 + threadIdx.x;
        float4 f = ((const float4*)x)[i];
        ushort4 o;
        o.x = f2bf(f.x); o.y = f2bf(f.y); o.z = f2bf(f.z); o.w = f2bf(f.w);
        ((ushort4*)xb)[i] = o;
    } else if (blockIdx.x < 3072) {
        int gid = (blockIdx.x - 2048) * 256 + threadIdx.x;
        int m   = gid >> 16;
        int idx = gid & 0xFFFF;
        const float* src = (m == 0) ? Wq : (m == 1) ? Wk : (m == 2) ? Wv : Wo;
        float4 f = ((const float4*)src)[idx];
        ushort4 o;
        o.x = f2bf(f.x); o.y = f2bf(f.y); o.z = f2bf(f.z); o.w = f2bf(f.w);
        if (m < 3) ((ushort4*)wqkv)[(m << 16) + idx] = o;
        else       ((ushort4*)wob)[idx] = o;
    } else {
        for (int i = threadIdx.x; i < 384; i += 256) {
            const float* src = (i < 128) ? bq : (i < 256) ? bk : bv;
            ((float4*)bqkv)[i] = ((const float4*)src)[i & 127];
        }
    }
}

// ---------------------------------------------------------------------------
// GEMM1: qkvb[4096,1536](bf16) = xb @ wqkv^T + bqkv.
// Tile 64x64, BK=64 (8 K-iters — measured best vs BK=128 in R9), swizzled
// glds staging (granule g of row r at physical g^(r&7), conflict-free
// fragment reads). 16 KB LDS -> 6 co-resident blocks/CU (grid-limited).
// ---------------------------------------------------------------------------
__global__ __launch_bounds__(256) void gemm_qkv(
    const unsigned short* __restrict__ A, const unsigned short* __restrict__ W,
    const float* __restrict__ bias, unsigned short* __restrict__ C)
{
    __shared__ unsigned short As[64 * 64];
    __shared__ unsigned short Bs[64 * 64];

    const int t  = threadIdx.x;
    const int m0 = blockIdx.x * 64;
    const int n0 = blockIdx.y * 64;          // global col in [0,1536)
    const int w  = t >> 6, l = t & 63;
    const int quad = l >> 4, lo = l & 15;

    const int lr = l >> 3;
    const int csw = ((l & 7) ^ lr) * 8;      // swizzled global col offset
    const unsigned short* Ag[2]; unsigned short* ldsA[2];
    const unsigned short* Bg[2]; unsigned short* ldsB[2];
    #pragma unroll
    for (int p = 0; p < 2; ++p) {
        Ag[p] = A + (size_t)(m0 + 16 * w + 8 * p + lr) * 512 + csw;
        ldsA[p] = &As[(16 * w + 8 * p) * 64];
        Bg[p] = W + (size_t)(n0 + 16 * w + 8 * p + lr) * 512 + csw;
        ldsB[p] = &Bs[(16 * w + 8 * p) * 64];
    }

    floatx4 acc[4];
    #pragma unroll
    for (int j = 0; j < 4; ++j) acc[j] = (floatx4)0.0f;

    const int swlo = lo & 7;

    for (int k0 = 0; k0 < 512; k0 += 64) {
        #pragma unroll
        for (int p = 0; p < 2; ++p) { glds16(Ag[p] + k0, ldsA[p]); glds16(Bg[p] + k0, ldsB[p]); }
        __syncthreads();

        #pragma unroll
        for (int ks = 0; ks < 2; ++ks) {
            const int cg = ((ks * 4 + quad) ^ swlo) * 8;
            short8 a = *(const short8*)(&As[(w * 16 + lo) * 64 + cg]);
            #pragma unroll
            for (int j = 0; j < 4; ++j) {
                short8 b = *(const short8*)(&Bs[(j * 16 + lo) * 64 + cg]);
                acc[j] = __builtin_amdgcn_mfma_f32_16x16x32_bf16(a, b, acc[j], 0, 0, 0);
            }
        }
        __syncthreads();
    }

    #pragma unroll
    for (int j = 0; j < 4; ++j) {
        int col = n0 + j * 16 + lo;
        float bv = bias[col];
        #pragma unroll
        for (int r = 0; r < 4; ++r) {
            int row = m0 + w * 16 + quad * 4 + r;
            C[(size_t)row * QKV_LD + col] = f2bf(acc[j][r] + bv);
        }
    }
}

// ---------------------------------------------------------------------------
// GEMM2: out[4096,512](f32) = attb(bf16) @ wob^T + bo. Same structure.
// ---------------------------------------------------------------------------
__global__ __launch_bounds__(256) void gemm_out(
    const unsigned short* __restrict__ attb, const unsigned short* __restrict__ wob,
    const float* __restrict__ bo, float* __restrict__ out)
{
    __shared__ unsigned short As[64 * 64];
    __shared__ unsigned short Bs[64 * 64];

    const int t  = threadIdx.x;
    const int m0 = blockIdx.x * 64;
    const int n0 = blockIdx.y * 64;
    const int w  = t >> 6, l = t & 63;
    const int quad = l >> 4, lo = l & 15;

    const int lr = l >> 3;
    const int csw = ((l & 7) ^ lr) * 8;
    const unsigned short* Ag[2]; unsigned short* ldsA[2];
    const unsigned short* Bg[2]; unsigned short* ldsB[2];
    #pragma unroll
    for (int p = 0; p < 2; ++p) {
        Ag[p] = attb + (size_t)(m0 + 16 * w + 8 * p + lr) * 512 + csw;
        ldsA[p] = &As[(16 * w + 8 * p) * 64];
        Bg[p] = wob + (size_t)(n0 + 16 * w + 8 * p + lr) * 512 + csw;
        ldsB[p] = &Bs[(16 * w + 8 * p) * 64];
    }

    floatx4 acc[4];
    #pragma unroll
    for (int j = 0; j < 4; ++j) acc[j] = (floatx4)0.0f;

    const int swlo = lo & 7;

    for (int k0 = 0; k0 < 512; k0 += 64) {
        #pragma unroll
        for (int p = 0; p < 2; ++p) { glds16(Ag[p] + k0, ldsA[p]); glds16(Bg[p] + k0, ldsB[p]); }
        __syncthreads();

        #pragma unroll
        for (int ks = 0; ks < 2; ++ks) {
            const int cg = ((ks * 4 + quad) ^ swlo) * 8;
            short8 a = *(const short8*)(&As[(w * 16 + lo) * 64 + cg]);
            #pragma unroll
            for (int j = 0; j < 4; ++j) {
                short8 b = *(const short8*)(&Bs[(j * 16 + lo) * 64 + cg]);
                acc[j] = __builtin_amdgcn_mfma_f32_16x16x32_bf16(a, b, acc[j], 0, 0, 0);
            }
        }
        __syncthreads();
    }

    #pragma unroll
    for (int j = 0; j < 4; ++j) {
        int col = n0 + j * 16 + lo;
        float bv = bo[col];
        #pragma unroll
        for (int r = 0; r < 4; ++r) {
            int row = m0 + w * 16 + quad * 4 + r;
            out[(size_t)row * 512 + col] = acc[j][r] + bv;
        }
    }
}

// ---------------------------------------------------------------------------
// MFMA local-window attention, band-restricted.
// ---------------------------------------------------------------------------
#define QLD 72
#define VLD 76

__global__ __launch_bounds__(256) void attn_mfma(
    const unsigned short* __restrict__ qkv, unsigned short* __restrict__ att)
{
    __shared__ unsigned short Qs[64][QLD];
    __shared__ unsigned short Ks[96][QLD];
    __shared__ unsigned short Vs[96][VLD];
    __shared__ unsigned short Pws[4][16][QLD];

    const int q0 = blockIdx.x * 64;
    const int bh = blockIdx.y;
    const int b = bh >> 3, h = bh & 7;
    const int t = threadIdx.x;
    const int wq = t >> 6, l = t & 63;
    const int quad = l >> 4, lo = l & 15;

    const size_t baseQ = (size_t)(b * T_) * QKV_LD + h * HD_;

    for (int c = t; c < 512; c += 256) {
        int row = c >> 3, cg = c & 7;
        *(short8*)(&Qs[row][cg * 8]) =
            *(const short8*)(&qkv[baseQ + (size_t)(q0 + row) * QKV_LD + cg * 8]);
    }
    for (int c = t; c < 768; c += 256) {
        int row = c >> 3, cg = c & 7;
        int g = q0 - WHALF_ + row;
        short8 kv = (short8)(short)0;
        if (g >= 0 && g < T_)
            kv = *(const short8*)(&qkv[baseQ + 512 + (size_t)g * QKV_LD + cg * 8]);
        *(short8*)(&Ks[row][cg * 8]) = kv;
    }
    for (int c = t; c < 768; c += 256) {
        int row = c >> 3, cg = c & 7;
        int g = q0 - WHALF_ + row;
        short8 vv = (short8)(short)0;
        if (g >= 0 && g < T_)
            vv = *(const short8*)(&qkv[baseQ + 1024 + (size_t)g * QKV_LD + cg * 8]);
        short4v lo4 = { vv[0], vv[1], vv[2], vv[3] };
        short4v hi4 = { vv[4], vv[5], vv[6], vv[7] };
        *(short4v*)(&Vs[row][cg * 8])     = lo4;
        *(short4v*)(&Vs[row][cg * 8 + 4]) = hi4;
    }
    __syncthreads();

    const int ks0 = wq >> 1;
    const int kb  = ks0 * 2;

    floatx4 S[4];
    #pragma unroll
    for (int tt = 0; tt < 4; ++tt) S[tt] = (floatx4)0.0f;
    short8 aq[2];
    #pragma unroll
    for (int ks = 0; ks < 2; ++ks)
        aq[ks] = *(const short8*)(&Qs[wq * 16 + lo][ks * 32 + quad * 8]);
    #pragma unroll
    for (int tt = 0; tt < 4; ++tt) {
        #pragma unroll
        for (int ks = 0; ks < 2; ++ks) {
            short8 bk8 = *(const short8*)(&Ks[(kb + tt) * 16 + lo][ks * 32 + quad * 8]);
            S[tt] = __builtin_amdgcn_mfma_f32_16x16x32_bf16(aq[ks], bk8, S[tt], 0, 0, 0);
        }
    }

    float inv_r[4];
    #pragma unroll
    for (int r = 0; r < 4; ++r) {
        int qi = q0 + wq * 16 + quad * 4 + r;
        float mx = -1e30f;
        float sv[4]; bool vd[4];
        #pragma unroll
        for (int tt = 0; tt < 4; ++tt) {
            int j = q0 - WHALF_ + (kb + tt) * 16 + lo;
            bool ok = (j >= qi - WHALF_) && (j < qi + WHALF_) && (j >= 0) && (j < T_);
            float s = S[tt][r] * 0.125f;
            sv[tt] = s; vd[tt] = ok;
            mx = (ok && s > mx) ? s : mx;
        }
        #pragma unroll
        for (int mm = 1; mm < 16; mm <<= 1) mx = fmaxf(mx, __shfl_xor(mx, mm, 16));
        float den = 0.f;
        #pragma unroll
        for (int tt = 0; tt < 4; ++tt) {
            float e = vd[tt] ? __expf(sv[tt] - mx) : 0.f;
            Pws[wq][quad * 4 + r][tt * 16 + lo] = f2bf(e);
            den += e;
        }
        #pragma unroll
        for (int mm = 1; mm < 16; mm <<= 1) den += __shfl_xor(den, mm, 16);
        inv_r[r] = 1.0f / den;
    }
    // Pws is wave-private: in-wave lgkmcnt ordering suffices, no barrier.

    floatx4 O[4];
    #pragma unroll
    for (int nt = 0; nt < 4; ++nt) O[nt] = (floatx4)0.0f;
    #pragma unroll
    for (int ksr = 0; ksr < 2; ++ksr) {
        short8 ap = *(const short8*)(&Pws[wq][lo][ksr * 32 + quad * 8]);
        const int krow = (ks0 + ksr) * 32 + quad * 8;
        #pragma unroll
        for (int nt = 0; nt < 4; ++nt) {
            short8 bv8;
            #pragma unroll
            for (int j = 0; j < 8; ++j)
                bv8[j] = (short)Vs[krow + j][nt * 16 + lo];
            O[nt] = __builtin_amdgcn_mfma_f32_16x16x32_bf16(ap, bv8, O[nt], 0, 0, 0);
        }
    }

    #pragma unroll
    for (int r = 0; r < 4; ++r) {
        int qi = q0 + wq * 16 + quad * 4 + r;
        size_t rowb = (size_t)(b * T_ + qi) * D_ + h * HD_;
        #pragma unroll
        for (int nt = 0; nt < 4; ++nt)
            att[rowb + nt * 16 + lo] = f2bf(O[nt][r] * inv_r[r]);
    }
}

// ---------------------------------------------------------------------------
extern "C" void kernel_launch(void* const* d_in, const int* in_sizes, int n_in,
                              void* d_out, int out_size, void* d_ws, size_t ws_size,
                              hipStream_t stream) {
    const float* x  = (const float*)d_in[0];
    const float* Wq = (const float*)d_in[1];
    const float* bq = (const float*)d_in[2];
    const float* Wk = (const float*)d_in[3];
    const float* bk = (const float*)d_in[4];
    const float* Wv = (const float*)d_in[5];
    const float* bv = (const float*)d_in[6];
    const float* Wo = (const float*)d_in[7];
    const float* bo = (const float*)d_in[8];
    float* out = (float*)d_out;

    char* ws = (char*)d_ws;
    unsigned short* xb   = (unsigned short*)(ws);                 //  4.00 MB
    unsigned short* wqkv = (unsigned short*)(ws +  4194304);      //  1.50 MB
    unsigned short* wob  = (unsigned short*)(ws +  5767168);      //  0.50 MB
    float*          bqkv = (float*)         (ws +  6291456);      //  6 KB
    unsigned short* qkvb = (unsigned short*)(ws +  6297600);      // 12.00 MB
    unsigned short* attb = (unsigned short*)(ws + 18880512);      //  4.00 MB

    cast_all<<<3073, 256, 0, stream>>>(x, Wq, Wk, Wv, Wo, bq, bk, bv,
                                       xb, wqkv, wob, bqkv);

    // fused QKV projection: 1536 blocks = 6/CU, BK=64
    gemm_qkv<<<dim3(Mtot / 64, QKV_LD / 64), 256, 0, stream>>>(
        xb, wqkv, bqkv, qkvb);

    // local attention (band-restricted MFMA)
    attn_mfma<<<dim3(T_ / 64, B_ * H_), 256, 0, stream>>>(qkvb, attb);

    // output projection: 512 blocks = 2/CU, BK=64
    gemm_out<<<dim3(Mtot / 64, D_ / 64), 256, 0, stream>>>(attb, wob, bo, out);
}